// Round 22
// baseline (1980.492 us; speedup 1.0000x reference)
//
#include <hip/hip_runtime.h>
#include <math.h>

#define NA 131072   // atoms
#define NE 262144   // edges
#define NG 4096     // graphs
#define FN 30
#define FE 11
#define H  256
#define H2 512
#define NL 5
#define BN_EPS 1e-5f
#define KP 32       // padded K for encoder/bond GEMMs

typedef _Float16 f16x8 __attribute__((ext_vector_type(8)));
typedef _Float16 f16x4 __attribute__((ext_vector_type(4)));
typedef float f32x4 __attribute__((ext_vector_type(4)));

// ---- private fallback workspace, allocated ONCE at library load ----
static char* g_buf = nullptr;
__attribute__((constructor)) static void _alloc_private_ws() {
    void* p = nullptr;
    if (hipMalloc(&p, (size_t)320 * 1024 * 1024) == hipSuccess) g_buf = (char*)p;
}

// ---------------- weight prep: transpose to fp16 [N][K], layer via grid.z ----------
__global__ __launch_bounds__(256) void prep_w_all(const float* __restrict__ w, int K, int N,
                                                  _Float16* __restrict__ hT) {
    const float* wl = w + (size_t)blockIdx.z * K * N;
    _Float16* hTl = hT + (size_t)blockIdx.z * K * N;
    __shared__ float t[32][33];
    const int k0 = blockIdx.x * 32, n0 = blockIdx.y * 32;
    const int tx = threadIdx.x & 31, ty = threadIdx.x >> 5;   // ty 0..7
    #pragma unroll
    for (int i = 0; i < 4; ++i)
        t[ty + i * 8][tx] = wl[(size_t)(k0 + ty + i * 8) * N + n0 + tx];
    __syncthreads();
    #pragma unroll
    for (int i = 0; i < 4; ++i)
        hTl[(size_t)(n0 + ty + i * 8) * K + k0 + tx] = (_Float16)t[tx][ty + i * 8];
}

// ---- small-K weight pad+transpose: w [K_IN][H] fp32 -> wT [H][KP] fp16 (zero pad) ----
__global__ __launch_bounds__(256) void prep_wpad(const float* __restrict__ w, int K_IN,
                                                 _Float16* __restrict__ wT) {
    const int n = threadIdx.x;
    #pragma unroll
    for (int kk = 0; kk < KP / 8; ++kk) {
        f16x8 v;
        #pragma unroll
        for (int j = 0; j < 8; ++j) {
            const int k = kk * 8 + j;
            v[j] = (k < K_IN) ? (_Float16)w[(size_t)k * H + n] : (_Float16)0.0f;
        }
        *(f16x8*)(wT + (size_t)n * KP + kk * 8) = v;
    }
}

// ---- x [NA][FN] fp32 -> x16 [NA][KP] fp16 padded ----
__global__ __launch_bounds__(256) void prep_x16(const float* __restrict__ x,
                                                _Float16* __restrict__ x16) {
    const int row = blockIdx.x * 64 + (threadIdx.x >> 2);
    const int g = threadIdx.x & 3;
    f16x8 v;
    #pragma unroll
    for (int j = 0; j < 8; ++j) {
        const int c = g * 8 + j;
        v[j] = (c < FN) ? (_Float16)x[(size_t)row * FN + c] : (_Float16)0.0f;
    }
    *(f16x8*)(x16 + (size_t)row * KP + g * 8) = v;
}

// ---- eattr permuted to CSR slot order + padded ----
__global__ __launch_bounds__(256) void prep_ea16(const float* __restrict__ eattr,
                                                 const int2* __restrict__ se,
                                                 _Float16* __restrict__ ea16) {
    const int t = blockIdx.x * 64 + (threadIdx.x >> 2);
    const int g = threadIdx.x & 3;
    const int e = se[t].y;
    f16x8 v;
    #pragma unroll
    for (int j = 0; j < 8; ++j) {
        const int c = g * 8 + j;
        v[j] = (c < FE) ? (_Float16)eattr[(size_t)e * FE + c] : (_Float16)0.0f;
    }
    *(f16x8*)(ea16 + (size_t)t * KP + g * 8) = v;
}

// ---------------- CSR build (once per call) ----------------
__global__ __launch_bounds__(256) void count_deg(const int* __restrict__ ei,
                                                 int* __restrict__ deg) {
    const int e = blockIdx.x * 256 + threadIdx.x;
    if (e < NE) atomicAdd(&deg[ei[NE + e]], 1);
}

__global__ __launch_bounds__(1024) void scan_deg(const int* __restrict__ deg,
                                                 int* __restrict__ rowptr,
                                                 int* __restrict__ cursor) {
    __shared__ int part[1024];
    const int t = threadIdx.x;
    const int base = t * 128;               // 1024*128 == NA
    int s = 0;
    #pragma unroll 8
    for (int i = 0; i < 128; ++i) s += deg[base + i];
    part[t] = s;
    __syncthreads();
    for (int off = 1; off < 1024; off <<= 1) {
        const int v = (t >= off) ? part[t - off] : 0;
        __syncthreads();
        part[t] += v;
        __syncthreads();
    }
    int run = (t == 0) ? 0 : part[t - 1];
    #pragma unroll 8
    for (int i = 0; i < 128; ++i) {
        rowptr[base + i] = run;
        cursor[base + i] = run;
        run += deg[base + i];
    }
    if (t == 1023) rowptr[NA] = run;        // == NE
}

__global__ __launch_bounds__(256) void fill_elist(const int* __restrict__ ei,
                                                  int* __restrict__ cursor,
                                                  int2* __restrict__ se) {
    const int e = blockIdx.x * 256 + threadIdx.x;
    if (e < NE) {
        const int src = ei[e];
        const int pos = atomicAdd(&cursor[ei[NE + e]], 1);
        se[pos] = make_int2(src, e);
    }
}

// ============ fused GINE + MLP layer (v3: ZERO-BARRIER K-loops) ==================
// Hout = relu(bn2(relu(bn1(z@w1))@w2)) + Hin,  z[dst] = (1+eps)Hin[dst] + sum relu(...)
// 64-row M-tile, 512 thr = 8 waves (2x4).  B fragments read DIRECTLY from global
// (weights L2-resident) -- NO LDS staging, NO barriers inside K-loops: waves slip
// freely, compiler pipelines loads with counted vmcnt.  A via Zt/Z1 in LDS (read-only
// between 3 block barriers).  LDS 64 KB -> 2 blocks/CU.
__global__ __launch_bounds__(512, 4) void fused_gine_mlp(
    const _Float16* __restrict__ Hin,     // [NA][256] layer input (residual source)
    _Float16* __restrict__ Hout,          // [NA][256] layer output
    const _Float16* __restrict__ eb,      // bond enc in CSR slot order [NE][256]
    const int2* __restrict__ se,          // {src, edge} per CSR slot
    const int* __restrict__ rowptr,
    const float* __restrict__ eps, int l,
    const _Float16* __restrict__ W1T,     // [512][256]
    const _Float16* __restrict__ W2T,     // [256][512]
    const float* __restrict__ b1l, const float* __restrict__ ig,
    const float* __restrict__ ib, const float* __restrict__ im,
    const float* __restrict__ iv,
    const float* __restrict__ b2l, const float* __restrict__ og,
    const float* __restrict__ ob, const float* __restrict__ om,
    const float* __restrict__ ov)
{
    __shared__ _Float16 Z1[64 * 512];     // 64 KB  (slots 0..63; Zt overlay 32..63)

    const int tid = threadIdx.x;
    const int m0 = blockIdx.x * 64;
    const int lane = tid & 63, wv = tid >> 6;
    const int lrow = lane & 15, lgrp = lane >> 4;
    const int wm2 = wv >> 2, wn2 = wv & 3;

    // -------- gather: z-tile -> Zt (Z1 slots 32..63) ------------------------------
    {
        const int c = lane * 4;
        const float sc = 1.0f + eps[l];
        #pragma unroll 1
        for (int d = 0; d < 8; ++d) {
            const int row = wv * 8 + d;            // in-tile row 0..63
            const int dst = m0 + row;
            const f16x4 hv = *(const f16x4*)(Hin + (size_t)dst * H + c);
            float4 a;
            a.x = sc * (float)hv.x; a.y = sc * (float)hv.y;
            a.z = sc * (float)hv.z; a.w = sc * (float)hv.w;
            const int lo = rowptr[dst], hi = rowptr[dst + 1];
            for (int t = lo; t < hi; ++t) {
                const int src = se[t].x;           // wave-uniform
                const f16x4 hs = *(const f16x4*)(Hin + (size_t)src * H + c);
                const f16x4 ev = *(const f16x4*)(eb + (size_t)t * H + c);
                a.x += fmaxf((float)hs.x + (float)ev.x, 0.0f);
                a.y += fmaxf((float)hs.y + (float)ev.y, 0.0f);
                a.z += fmaxf((float)hs.z + (float)ev.z, 0.0f);
                a.w += fmaxf((float)hs.w + (float)ev.w, 0.0f);
            }
            f16x4 o;
            o.x = (_Float16)a.x; o.y = (_Float16)a.y;
            o.z = (_Float16)a.z; o.w = (_Float16)a.w;
            const int slot = 32 + ((c >> 3) ^ (row & 7));
            *(f16x4*)&Z1[row * 512 + (slot << 3) + (c & 7)] = o;
        }
    }
    __syncthreads();                      // [barrier 1] Zt complete

    const int arA = wm2 * 32 + lrow;      // A rows (in-tile): arA, arA+16
    const f32x4 zero4 = {0.0f, 0.0f, 0.0f, 0.0f};

    // ---------------- phase 1: Z1(slots 0..63) = relu(bn1(z @ w1 + b1)) ------------
    // acc for BOTH 256-col halves live simultaneously (h epilogues deferred so the
    // only barrier sits between "all Zt reads done" and "Zt slots overwritten").
    float scl1[2][4], shf1[2][4];
    #pragma unroll
    for (int h = 0; h < 2; ++h)
        #pragma unroll
        for (int ni = 0; ni < 4; ++ni) {
            const int c = h * 256 + wn2 * 64 + ni * 16 + lrow;
            const float s = ig[c] * rsqrtf(iv[c] + BN_EPS);
            scl1[h][ni] = s;
            shf1[h][ni] = s * (b1l[c] - im[c]) + ib[c];
        }
    f32x4 acc1[2][2][4];                  // [h][mi][ni]
    #pragma unroll
    for (int h = 0; h < 2; ++h)
        #pragma unroll
        for (int i = 0; i < 2; ++i)
            #pragma unroll
            for (int j = 0; j < 4; ++j) acc1[h][i][j] = zero4;

    #pragma unroll
    for (int h = 0; h < 2; ++h) {
        const _Float16* Bb = W1T + (size_t)h * 256 * 256;
        #pragma unroll
        for (int ks = 0; ks < 8; ++ks) {       // NO barriers: waves slip freely
            f16x8 af[2], bf[4];
            #pragma unroll
            for (int mi = 0; mi < 2; ++mi) {
                const int ar = arA + mi * 16;
                const int slot = 32 + ((ks * 4 + lgrp) ^ (ar & 7));
                af[mi] = *(const f16x8*)&Z1[ar * 512 + (slot << 3)];
            }
            #pragma unroll
            for (int ni = 0; ni < 4; ++ni) {
                const int br = wn2 * 64 + ni * 16 + lrow;
                bf[ni] = *(const f16x8*)(Bb + (size_t)br * 256 + ks * 32 + lgrp * 8);
            }
            #pragma unroll
            for (int mi = 0; mi < 2; ++mi)
                #pragma unroll
                for (int ni = 0; ni < 4; ++ni)
                    acc1[h][mi][ni] = __builtin_amdgcn_mfma_f32_16x16x32_f16(af[mi], bf[ni], acc1[h][mi][ni], 0, 0, 0);
        }
    }
    __syncthreads();                      // [barrier 2] all Zt reads done
    #pragma unroll
    for (int h = 0; h < 2; ++h)
        #pragma unroll
        for (int mi = 0; mi < 2; ++mi)
            #pragma unroll
            for (int j = 0; j < 4; ++j) {
                const int row = wm2 * 32 + mi * 16 + lgrp * 4 + j;
                #pragma unroll
                for (int ni = 0; ni < 4; ++ni) {
                    const int col = h * 256 + wn2 * 64 + ni * 16 + lrow;
                    const int slot = (col >> 3) ^ (row & 7);
                    Z1[row * 512 + (slot << 3) + (col & 7)] =
                        (_Float16)fmaxf(scl1[h][ni] * acc1[h][mi][ni][j] + shf1[h][ni], 0.0f);
                }
            }
    __syncthreads();                      // [barrier 3] Z1 complete

    // ---------------- phase 2: Hout = relu(bn2(Z1 @ w2 + b2)) + Hin ----------------
    float scl2[4], shf2[4];
    #pragma unroll
    for (int ni = 0; ni < 4; ++ni) {
        const int c = wn2 * 64 + ni * 16 + lrow;
        const float s = og[c] * rsqrtf(ov[c] + BN_EPS);
        scl2[ni] = s;
        shf2[ni] = s * (b2l[c] - om[c]) + ob[c];
    }
    f32x4 acc2[2][4];
    #pragma unroll
    for (int i = 0; i < 2; ++i)
        #pragma unroll
        for (int j = 0; j < 4; ++j) acc2[i][j] = zero4;

    #pragma unroll
    for (int ks = 0; ks < 16; ++ks) {          // NO barriers
        const int k0 = ks * 32;
        f16x8 af[2], bf[4];
        #pragma unroll
        for (int mi = 0; mi < 2; ++mi) {
            const int ar = arA + mi * 16;
            const int slot = ((k0 >> 3) + lgrp) ^ (ar & 7);
            af[mi] = *(const f16x8*)&Z1[ar * 512 + (slot << 3)];
        }
        #pragma unroll
        for (int ni = 0; ni < 4; ++ni) {
            const int br = wn2 * 64 + ni * 16 + lrow;
            bf[ni] = *(const f16x8*)(W2T + (size_t)br * 512 + k0 + lgrp * 8);
        }
        #pragma unroll
        for (int mi = 0; mi < 2; ++mi)
            #pragma unroll
            for (int ni = 0; ni < 4; ++ni)
                acc2[mi][ni] = __builtin_amdgcn_mfma_f32_16x16x32_f16(af[mi], bf[ni], acc2[mi][ni], 0, 0, 0);
    }

    #pragma unroll
    for (int mi = 0; mi < 2; ++mi)
        #pragma unroll
        for (int j = 0; j < 4; ++j) {
            const int row = m0 + wm2 * 32 + mi * 16 + lgrp * 4 + j;
            #pragma unroll
            for (int ni = 0; ni < 4; ++ni) {
                const int col = wn2 * 64 + ni * 16 + lrow;
                float v = fmaxf(scl2[ni] * acc2[mi][ni][j] + shf2[ni], 0.0f);
                v += (float)Hin[(size_t)row * H + col];
                Hout[(size_t)row * H + col] = (_Float16)v;
            }
        }
}

// ---------------- fp16 MFMA GEMM (encoder / ebond / classifier) ----------------
// EPI 0: relu(bn(acc+bias))  EPI 2: acc+bias only
template <int KDIM, int EPI>
__global__ __launch_bounds__(256, 4) void gemm_f16(
    const _Float16* __restrict__ A,
    const _Float16* __restrict__ BT,
    int Ncols,
    const float* __restrict__ bias, const float* __restrict__ bng,
    const float* __restrict__ bnb, const float* __restrict__ bnm,
    const float* __restrict__ bnv,
    _Float16* __restrict__ C16, const _Float16* __restrict__ res)
{
    __shared__ f16x8 As[2][512];
    __shared__ f16x8 Bs[2][512];

    const int tid = threadIdx.x;
    const int nt = Ncols >> 7;
    const int nwg = gridDim.x, orig = blockIdx.x;
    const int q = nwg >> 3, r = nwg & 7;
    const int xcd = orig & 7, rk = orig >> 3;
    const int wg = (xcd < r ? xcd * (q + 1) : r * (q + 1) + (xcd - r) * q) + rk;
    const int m0 = (wg / nt) * 128;
    const int n0 = (wg % nt) * 128;

    const int wid = tid >> 6, lane = tid & 63;
    const int wm = wid >> 1, wn = wid & 1;
    const int lrow = lane & 15, lgrp = lane >> 4;
    const int r0s = tid >> 2;
    const int kq  = tid & 3;
    const int sw0 = kq ^ ((r0s >> 1) & 3);
    const int sw1 = kq ^ (((r0s + 64) >> 1) & 3);

    f32x4 acc[4][4];
    const f32x4 zero4 = {0.0f, 0.0f, 0.0f, 0.0f};
    #pragma unroll
    for (int i = 0; i < 4; ++i)
        #pragma unroll
        for (int j = 0; j < 4; ++j) acc[i][j] = zero4;

    f16x8 a0, a1, b0, b1;
    #define SLOAD(K0)                                                             \
        a0 = *(const f16x8*)(A  + (size_t)(m0 + r0s) * KDIM + (K0) + kq * 8);     \
        a1 = *(const f16x8*)(A  + (size_t)(m0 + r0s + 64) * KDIM + (K0) + kq * 8);\
        b0 = *(const f16x8*)(BT + (size_t)(n0 + r0s) * KDIM + (K0) + kq * 8);     \
        b1 = *(const f16x8*)(BT + (size_t)(n0 + r0s + 64) * KDIM + (K0) + kq * 8);
    #define SWRITE(CUR)                                                           \
        As[CUR][r0s * 4 + sw0] = a0;  As[CUR][(r0s + 64) * 4 + sw1] = a1;         \
        Bs[CUR][r0s * 4 + sw0] = b0;  Bs[CUR][(r0s + 64) * 4 + sw1] = b1;

    SLOAD(0);
    int cur = 0;
    for (int k0 = 0; k0 < KDIM; k0 += 32) {
        SWRITE(cur);
        __syncthreads();
        if (k0 + 32 < KDIM) { SLOAD(k0 + 32); }
        f16x8 af[4], bf[4];
        #pragma unroll
        for (int mi = 0; mi < 4; ++mi) {
            const int ar = wm * 64 + mi * 16 + lrow;
            af[mi] = As[cur][ar * 4 + (lgrp ^ ((ar >> 1) & 3))];
        }
        #pragma unroll
        for (int ni = 0; ni < 4; ++ni) {
            const int br = wn * 64 + ni * 16 + lrow;
            bf[ni] = Bs[cur][br * 4 + (lgrp ^ ((br >> 1) & 3))];
        }
        #pragma unroll
        for (int mi = 0; mi < 4; ++mi)
            #pragma unroll
            for (int ni = 0; ni < 4; ++ni)
                acc[mi][ni] = __builtin_amdgcn_mfma_f32_16x16x32_f16(af[mi], bf[ni], acc[mi][ni], 0, 0, 0);
        cur ^= 1;
    }
    #undef SLOAD
    #undef SWRITE

    float scl[4], shf[4];
    #pragma unroll
    for (int ni = 0; ni < 4; ++ni) {
        const int c = n0 + wn * 64 + ni * 16 + lrow;
        if (EPI == 2) {
            scl[ni] = 1.0f;
            shf[ni] = bias[c];
        } else {
            const float s = bng[c] * rsqrtf(bnv[c] + BN_EPS);
            scl[ni] = s;
            shf[ni] = s * (bias[c] - bnm[c]) + bnb[c];
        }
    }
    #pragma unroll
    for (int mi = 0; mi < 4; ++mi)
        #pragma unroll
        for (int j = 0; j < 4; ++j) {
            const int row = m0 + wm * 64 + mi * 16 + lgrp * 4 + j;
            #pragma unroll
            for (int ni = 0; ni < 4; ++ni) {
                const int col = n0 + wn * 64 + ni * 16 + lrow;
                float v = scl[ni] * acc[mi][ni][j] + shf[ni];
                if (EPI != 2) v = fmaxf(v, 0.0f);
                C16[(size_t)row * Ncols + col] = (_Float16)v;
            }
        }
}

// ---------------- pooling: mean + max per graph, fp16 out ----------------
__global__ __launch_bounds__(H) void pool_kernel(const _Float16* __restrict__ h16,
                                                 const int* __restrict__ batch,
                                                 _Float16* __restrict__ p16) {
    const int g = blockIdx.x;
    const int c = threadIdx.x;
    int lo, hi;
    {
        int a = 0, b = NA;
        while (a < b) { int mid = (a + b) >> 1; if (batch[mid] < g) a = mid + 1; else b = mid; }
        lo = a;
        b = NA;
        while (a < b) { int mid = (a + b) >> 1; if (batch[mid] < g + 1) a = mid + 1; else b = mid; }
        hi = a;
    }
    float sum = 0.0f, mx = -INFINITY;
    for (int n = lo; n < hi; ++n) {
        const float v = (float)h16[(size_t)n * H + c];
        sum += v;
        mx = fmaxf(mx, v);
    }
    const int cnt = hi - lo;
    const float mean = (cnt > 0) ? sum / (float)cnt : 0.0f;
    if (cnt == 0) mx = 0.0f;
    p16[(size_t)g * H2 + c] = (_Float16)mean;
    p16[(size_t)g * H2 + H + c] = (_Float16)mx;
}

// ---------------- final linear ----------------
__global__ __launch_bounds__(64) void final_out(const _Float16* __restrict__ q2,
                                                const float* __restrict__ w,
                                                const float* __restrict__ b,
                                                float* __restrict__ out) {
    const int g = blockIdx.x;
    const int lane = threadIdx.x;
    float acc = (float)q2[(size_t)g * 128 + lane] * w[lane]
              + (float)q2[(size_t)g * 128 + 64 + lane] * w[64 + lane];
    #pragma unroll
    for (int off = 32; off > 0; off >>= 1) acc += __shfl_down(acc, off);
    if (lane == 0) out[g] = acc + b[0];
}

// ---------------- launch ----------------
extern "C" void kernel_launch(void* const* d_in, const int* in_sizes, int n_in,
                              void* d_out, int out_size, void* d_ws, size_t ws_size,
                              hipStream_t stream) {
    const float* x      = (const float*)d_in[0];
    const int*   ei     = (const int*)d_in[1];
    const int*   batch  = (const int*)d_in[2];
    const float* eattr  = (const float*)d_in[3];
    const float* enc_w  = (const float*)d_in[4];
    const float* enc_b  = (const float*)d_in[5];
    const float* bond_w = (const float*)d_in[6];
    const float* bond_b = (const float*)d_in[7];
    const float* eps    = (const float*)d_in[8];
    const float* w1     = (const float*)d_in[9];
    const float* b1     = (const float*)d_in[10];
    const float* ibn_g  = (const float*)d_in[11];
    const float* ibn_b  = (const float*)d_in[12];
    const float* ibn_m  = (const float*)d_in[13];
    const float* ibn_v  = (const float*)d_in[14];
    const float* w2     = (const float*)d_in[15];
    const float* b2     = (const float*)d_in[16];
    const float* obn_g  = (const float*)d_in[17];
    const float* obn_b  = (const float*)d_in[18];
    const float* obn_m  = (const float*)d_in[19];
    const float* obn_v  = (const float*)d_in[20];
    const float* cw1    = (const float*)d_in[21];
    const float* cb1    = (const float*)d_in[22];
    const float* c1g    = (const float*)d_in[23];
    const float* c1b    = (const float*)d_in[24];
    const float* c1m    = (const float*)d_in[25];
    const float* c1v    = (const float*)d_in[26];
    const float* cw2    = (const float*)d_in[27];
    const float* cb2    = (const float*)d_in[28];
    const float* c2g    = (const float*)d_in[29];
    const float* c2b    = (const float*)d_in[30];
    const float* c2m    = (const float*)d_in[31];
    const float* c2v    = (const float*)d_in[32];
    const float* cw3    = (const float*)d_in[33];
    const float* cb3    = (const float*)d_in[34];
    float* out = (float*)d_out;

    // ---- workspace layout (fp16 datapath; h ping-pong hA/hB; no z) ----
    const size_t WTE       = (size_t)NL * H * H2;
    const size_t CW1E      = (size_t)H2 * H;
    const size_t CW2E      = (size_t)H * (H / 2);
    const size_t EWE       = (size_t)H * KP;
    const size_t BWE       = (size_t)H * KP;
    const size_t wt_bytes  = (2 * WTE + CW1E + CW2E + EWE + BWE) * 2;
    const size_t csr_words = (size_t)3 * NA + 1 + 2 * (size_t)NE + 63;
    const size_t csr_bytes = csr_words * 4;
    const size_t eb_bytes  = (size_t)NE * H * 2;             // 134 MB
    const size_t hx_bytes  = (size_t)NA * H * 2;             // 67 MB each
    const size_t x16_bytes = (size_t)NA * KP * 2;            // 8.4 MB
    const size_t ea_bytes  = (size_t)NE * KP * 2;            // 16.8 MB
    const size_t need_full = wt_bytes + csr_bytes + eb_bytes + 2 * hx_bytes
                           + x16_bytes + ea_bytes;

    char* buf;
    if (ws_size >= need_full) { buf = (char*)d_ws; }
    else if (g_buf)           { buf = g_buf; }
    else                      { buf = (char*)d_ws; }

    _Float16* w1T  = (_Float16*)buf;
    _Float16* w2T  = w1T + WTE;
    _Float16* cw1T = w2T + WTE;
    _Float16* cw2T = cw1T + CW1E;
    _Float16* encT = cw2T + CW2E;
    _Float16* bndT = encT + EWE;
    int*  deg    = (int*)(buf + wt_bytes);
    int*  rowptr = deg + NA;
    int*  cursor = rowptr + NA + 1;
    int2* se     = (int2*)(cursor + NA);
    _Float16* eb  = (_Float16*)(buf + wt_bytes + csr_bytes);
    _Float16* hA  = (_Float16*)((char*)eb + eb_bytes);
    _Float16* hB  = (_Float16*)((char*)hA + hx_bytes);
    _Float16* x16  = (_Float16*)((char*)hB + hx_bytes);
    _Float16* ea16 = (_Float16*)((char*)x16 + x16_bytes);

    // after 5 layers (A->B->A->B->A->B) final state is in hB; classifier aliases hA
    _Float16* p16 = hA;                       // NG*H2  (hA dead after layer 4)
    _Float16* q1  = p16 + (size_t)NG * H2;    // NG*H
    _Float16* q2  = q1 + (size_t)NG * H;      // NG*(H/2)

    // ---- weight prep (transpose to fp16), once per call ----
    prep_w_all<<<dim3(H / 32, H2 / 32, NL), 256, 0, stream>>>(w1, H, H2, w1T);
    prep_w_all<<<dim3(H2 / 32, H / 32, NL), 256, 0, stream>>>(w2, H2, H, w2T);
    prep_w_all<<<dim3(H2 / 32, H / 32, 1), 256, 0, stream>>>(cw1, H2, H, cw1T);
    prep_w_all<<<dim3(H / 32, H / 64, 1), 256, 0, stream>>>(cw2, H, H / 2, cw2T);
    prep_wpad<<<1, 256, 0, stream>>>(enc_w, FN, encT);
    prep_wpad<<<1, 256, 0, stream>>>(bond_w, FE, bndT);

    // ---- CSR build ----
    hipMemsetAsync(deg, 0, (size_t)NA * 4, stream);
    count_deg<<<NE / 256, 256, 0, stream>>>(ei, deg);
    scan_deg<<<1, 1024, 0, stream>>>(deg, rowptr, cursor);
    fill_elist<<<NE / 256, 256, 0, stream>>>(ei, cursor, se);

    // ---- inputs to fp16 (padded K=32) ----
    prep_x16<<<NA / 64, 256, 0, stream>>>(x, x16);
    prep_ea16<<<NE / 64, 256, 0, stream>>>(eattr, se, ea16);

    // ---- encoder + bond encoding as MFMA GEMMs ----
    gemm_f16<KP, 2><<<(NA / 128) * (H / 128), 256, 0, stream>>>(
        x16, encT, H, enc_b, nullptr, nullptr, nullptr, nullptr, hA, nullptr);
    gemm_f16<KP, 2><<<(NE / 128) * (H / 128), 256, 0, stream>>>(
        ea16, bndT, H, bond_b, nullptr, nullptr, nullptr, nullptr, eb, nullptr);

    for (int l = 0; l < NL; ++l) {
        _Float16* hin  = (l & 1) ? hB : hA;
        _Float16* hout = (l & 1) ? hA : hB;
        fused_gine_mlp<<<NA / 64, 512, 0, stream>>>(
            hin, hout, eb, se, rowptr, eps, l,
            w1T + (size_t)l * H * H2, w2T + (size_t)l * H2 * H,
            b1 + (size_t)l * H2, ibn_g + (size_t)l * H2, ibn_b + (size_t)l * H2,
            ibn_m + (size_t)l * H2, ibn_v + (size_t)l * H2,
            b2 + (size_t)l * H, obn_g + (size_t)l * H, obn_b + (size_t)l * H,
            obn_m + (size_t)l * H, obn_v + (size_t)l * H);
    }

    pool_kernel<<<NG, H, 0, stream>>>(hB, batch, p16);
    gemm_f16<H2, 0><<<(NG / 128) * (H / 128), 256, 0, stream>>>(
        p16, cw1T, H, cb1, c1g, c1b, c1m, c1v, q1, nullptr);
    gemm_f16<H, 0><<<(NG / 128) * ((H / 2) / 128), 256, 0, stream>>>(
        q1, cw2T, H / 2, cb2, c2g, c2b, c2m, c2v, q2, nullptr);
    final_out<<<NG, 64, 0, stream>>>(q2, cw3, cb3, out);
}

// Round 23
// 1160.270 us; speedup vs baseline: 1.7069x; 1.7069x over previous
//
#include <hip/hip_runtime.h>
#include <math.h>

#define NA 131072   // atoms
#define NE 262144   // edges
#define NG 4096     // graphs
#define FN 30
#define FE 11
#define H  256
#define H2 512
#define NL 5
#define BN_EPS 1e-5f
#define KP 32       // padded K for encoder/bond GEMMs

typedef _Float16 f16x8 __attribute__((ext_vector_type(8)));
typedef _Float16 f16x4 __attribute__((ext_vector_type(4)));
typedef float f32x4 __attribute__((ext_vector_type(4)));

// ---- private fallback workspace, allocated ONCE at library load ----
static char* g_buf = nullptr;
__attribute__((constructor)) static void _alloc_private_ws() {
    void* p = nullptr;
    if (hipMalloc(&p, (size_t)320 * 1024 * 1024) == hipSuccess) g_buf = (char*)p;
}

// ---------------- weight prep: transpose to fp16 [N][K], layer via grid.z ----------
__global__ __launch_bounds__(256) void prep_w_all(const float* __restrict__ w, int K, int N,
                                                  _Float16* __restrict__ hT) {
    const float* wl = w + (size_t)blockIdx.z * K * N;
    _Float16* hTl = hT + (size_t)blockIdx.z * K * N;
    __shared__ float t[32][33];
    const int k0 = blockIdx.x * 32, n0 = blockIdx.y * 32;
    const int tx = threadIdx.x & 31, ty = threadIdx.x >> 5;   // ty 0..7
    #pragma unroll
    for (int i = 0; i < 4; ++i)
        t[ty + i * 8][tx] = wl[(size_t)(k0 + ty + i * 8) * N + n0 + tx];
    __syncthreads();
    #pragma unroll
    for (int i = 0; i < 4; ++i)
        hTl[(size_t)(n0 + ty + i * 8) * K + k0 + tx] = (_Float16)t[tx][ty + i * 8];
}

// ---- small-K weight pad+transpose: w [K_IN][H] fp32 -> wT [H][KP] fp16 (zero pad) ----
__global__ __launch_bounds__(256) void prep_wpad(const float* __restrict__ w, int K_IN,
                                                 _Float16* __restrict__ wT) {
    const int n = threadIdx.x;
    #pragma unroll
    for (int kk = 0; kk < KP / 8; ++kk) {
        f16x8 v;
        #pragma unroll
        for (int j = 0; j < 8; ++j) {
            const int k = kk * 8 + j;
            v[j] = (k < K_IN) ? (_Float16)w[(size_t)k * H + n] : (_Float16)0.0f;
        }
        *(f16x8*)(wT + (size_t)n * KP + kk * 8) = v;
    }
}

// ---- x [NA][FN] fp32 -> x16 [NA][KP] fp16 padded ----
__global__ __launch_bounds__(256) void prep_x16(const float* __restrict__ x,
                                                _Float16* __restrict__ x16) {
    const int row = blockIdx.x * 64 + (threadIdx.x >> 2);
    const int g = threadIdx.x & 3;
    f16x8 v;
    #pragma unroll
    for (int j = 0; j < 8; ++j) {
        const int c = g * 8 + j;
        v[j] = (c < FN) ? (_Float16)x[(size_t)row * FN + c] : (_Float16)0.0f;
    }
    *(f16x8*)(x16 + (size_t)row * KP + g * 8) = v;
}

// ---- eattr permuted to CSR slot order + padded ----
__global__ __launch_bounds__(256) void prep_ea16(const float* __restrict__ eattr,
                                                 const int2* __restrict__ se,
                                                 _Float16* __restrict__ ea16) {
    const int t = blockIdx.x * 64 + (threadIdx.x >> 2);
    const int g = threadIdx.x & 3;
    const int e = se[t].y;
    f16x8 v;
    #pragma unroll
    for (int j = 0; j < 8; ++j) {
        const int c = g * 8 + j;
        v[j] = (c < FE) ? (_Float16)eattr[(size_t)e * FE + c] : (_Float16)0.0f;
    }
    *(f16x8*)(ea16 + (size_t)t * KP + g * 8) = v;
}

// ---------------- CSR build (once per call) ----------------
__global__ __launch_bounds__(256) void count_deg(const int* __restrict__ ei,
                                                 int* __restrict__ deg) {
    const int e = blockIdx.x * 256 + threadIdx.x;
    if (e < NE) atomicAdd(&deg[ei[NE + e]], 1);
}

__global__ __launch_bounds__(1024) void scan_deg(const int* __restrict__ deg,
                                                 int* __restrict__ rowptr,
                                                 int* __restrict__ cursor) {
    __shared__ int part[1024];
    const int t = threadIdx.x;
    const int base = t * 128;               // 1024*128 == NA
    int s = 0;
    #pragma unroll 8
    for (int i = 0; i < 128; ++i) s += deg[base + i];
    part[t] = s;
    __syncthreads();
    for (int off = 1; off < 1024; off <<= 1) {
        const int v = (t >= off) ? part[t - off] : 0;
        __syncthreads();
        part[t] += v;
        __syncthreads();
    }
    int run = (t == 0) ? 0 : part[t - 1];
    #pragma unroll 8
    for (int i = 0; i < 128; ++i) {
        rowptr[base + i] = run;
        cursor[base + i] = run;
        run += deg[base + i];
    }
    if (t == 1023) rowptr[NA] = run;        // == NE
}

__global__ __launch_bounds__(256) void fill_elist(const int* __restrict__ ei,
                                                  int* __restrict__ cursor,
                                                  int2* __restrict__ se) {
    const int e = blockIdx.x * 256 + threadIdx.x;
    if (e < NE) {
        const int src = ei[e];
        const int pos = atomicAdd(&cursor[ei[NE + e]], 1);
        se[pos] = make_int2(src, e);
    }
}

// ================= fused GINE + MLP layer (r21 best-known config) =================
// Hout = relu(bn2(relu(bn1(z@w1))@w2)) + Hin,  z[dst] = (1+eps)Hin[dst] + sum relu(...)
// 64-row M-tile, 512 thr = 8 waves (2x4).  Gather: 2 groups of 4 rows per wave with
// 4 independent dependent-chains in flight.  Zt overlay in Z1 slots 32..63.
// Hin/Hout ping-pong.  LDS 80 KB -> 2 blocks/CU.
__global__ __launch_bounds__(512, 4) void fused_gine_mlp(
    const _Float16* __restrict__ Hin,     // [NA][256] layer input (residual source)
    _Float16* __restrict__ Hout,          // [NA][256] layer output
    const _Float16* __restrict__ eb,      // bond enc in CSR slot order [NE][256]
    const int2* __restrict__ se,          // {src, edge} per CSR slot
    const int* __restrict__ rowptr,
    const float* __restrict__ eps, int l,
    const _Float16* __restrict__ W1T,     // [512][256]
    const _Float16* __restrict__ W2T,     // [256][512]
    const float* __restrict__ b1l, const float* __restrict__ ig,
    const float* __restrict__ ib, const float* __restrict__ im,
    const float* __restrict__ iv,
    const float* __restrict__ b2l, const float* __restrict__ og,
    const float* __restrict__ ob, const float* __restrict__ om,
    const float* __restrict__ ov)
{
    __shared__ f16x8 Bs[1024];            // 16 KB  (B tile 256x32, single buffer)
    __shared__ _Float16 Z1[64 * 512];     // 64 KB  (slots 0..63; Zt overlay 32..63)

    const int tid = threadIdx.x;
    const int m0 = blockIdx.x * 64;
    const int lane = tid & 63, wv = tid >> 6;
    const int lrow = lane & 15, lgrp = lane >> 4;
    const int wm2 = wv >> 2, wn2 = wv & 3;
    const int kq = tid & 3;
    const int brow = tid >> 2;            // 0..127
    const int bsw0 = brow * 4 + (kq ^ ((brow >> 1) & 3));
    const int bsw1 = (brow + 128) * 4 + (kq ^ (((brow + 128) >> 1) & 3));

    f16x8 bA, bB;
    #define SLOAD_B(BASE, K0, KD) { \
        bA = *(const f16x8*)((BASE) + (size_t)brow * (KD) + (K0) + kq * 8); \
        bB = *(const f16x8*)((BASE) + (size_t)(brow + 128) * (KD) + (K0) + kq * 8); }
    #define SWRITE_B() { Bs[bsw0] = bA; Bs[bsw1] = bB; }

    SLOAD_B(W1T, 0, 256);                 // first weight panel flies under the gather

    // -------- gather: z-tile -> Zt (Z1 slots 32..63), 4 chains in flight ---------
    {
        const int c = lane * 4;
        const float sc = 1.0f + eps[l];
        #pragma unroll 1
        for (int g4 = 0; g4 < 2; ++g4) {
            const int rb = wv * 8 + g4 * 4;          // in-tile rows rb..rb+3
            int tcur[4], tend[4];
            float4 a[4];
            #pragma unroll
            for (int i = 0; i < 4; ++i) {
                const int dst = m0 + rb + i;
                tcur[i] = rowptr[dst];
                tend[i] = rowptr[dst + 1];
                const f16x4 hv = *(const f16x4*)(Hin + (size_t)dst * H + c);
                a[i].x = sc * (float)hv.x; a[i].y = sc * (float)hv.y;
                a[i].z = sc * (float)hv.z; a[i].w = sc * (float)hv.w;
            }
            bool more = (tcur[0] < tend[0]) || (tcur[1] < tend[1]) ||
                        (tcur[2] < tend[2]) || (tcur[3] < tend[3]);
            while (more) {
                #pragma unroll
                for (int i = 0; i < 4; ++i) {
                    if (tcur[i] < tend[i]) {          // wave-uniform branch
                        const int t = tcur[i];
                        const int src = se[t].x;
                        const f16x4 hs = *(const f16x4*)(Hin + (size_t)src * H + c);
                        const f16x4 ev = *(const f16x4*)(eb + (size_t)t * H + c);
                        a[i].x += fmaxf((float)hs.x + (float)ev.x, 0.0f);
                        a[i].y += fmaxf((float)hs.y + (float)ev.y, 0.0f);
                        a[i].z += fmaxf((float)hs.z + (float)ev.z, 0.0f);
                        a[i].w += fmaxf((float)hs.w + (float)ev.w, 0.0f);
                        ++tcur[i];
                    }
                }
                more = (tcur[0] < tend[0]) || (tcur[1] < tend[1]) ||
                       (tcur[2] < tend[2]) || (tcur[3] < tend[3]);
            }
            #pragma unroll
            for (int i = 0; i < 4; ++i) {
                const int row = rb + i;
                f16x4 o;
                o.x = (_Float16)a[i].x; o.y = (_Float16)a[i].y;
                o.z = (_Float16)a[i].z; o.w = (_Float16)a[i].w;
                const int slot = 32 + ((c >> 3) ^ (row & 7));
                *(f16x4*)&Z1[row * 512 + (slot << 3) + (c & 7)] = o;
            }
        }
    }
    __syncthreads();                      // Zt complete

    const int arA = wm2 * 32 + lrow;      // A rows (in-tile): arA, arA+16
    const f32x4 zero4 = {0.0f, 0.0f, 0.0f, 0.0f};

    // ---------------- phase 1: Z1(slots 0..63) = relu(bn1(z @ w1 + b1)) ------------
    #pragma unroll 1
    for (int h = 0; h < 2; ++h) {
        const _Float16* Bb = W1T + (size_t)h * 256 * 256;
        float scl1[4], shf1[4];
        #pragma unroll
        for (int ni = 0; ni < 4; ++ni) {
            const int c = h * 256 + wn2 * 64 + ni * 16 + lrow;
            const float s = ig[c] * rsqrtf(iv[c] + BN_EPS);
            scl1[ni] = s;
            shf1[ni] = s * (b1l[c] - im[c]) + ib[c];
        }
        f32x4 acc[2][4];
        #pragma unroll
        for (int i = 0; i < 2; ++i)
            #pragma unroll
            for (int j = 0; j < 4; ++j) acc[i][j] = zero4;

        if (h == 1) SLOAD_B(Bb, 0, 256);        // h==0 preloaded before gather
        #pragma unroll 1
        for (int ks = 0; ks < 8; ++ks) {
            __syncthreads();                    // (a) prior Bs reads done
            SWRITE_B();
            __syncthreads();                    // (b) Bs ready
            if (ks + 1 < 8) SLOAD_B(Bb, (ks + 1) * 32, 256);
            f16x8 af[2], bf[4];
            #pragma unroll
            for (int mi = 0; mi < 2; ++mi) {
                const int ar = arA + mi * 16;
                const int slot = 32 + ((ks * 4 + lgrp) ^ (ar & 7));
                af[mi] = *(const f16x8*)&Z1[ar * 512 + (slot << 3)];
            }
            #pragma unroll
            for (int ni = 0; ni < 4; ++ni) {
                const int br = wn2 * 64 + ni * 16 + lrow;
                bf[ni] = Bs[br * 4 + (lgrp ^ ((br >> 1) & 3))];
            }
            #pragma unroll
            for (int mi = 0; mi < 2; ++mi)
                #pragma unroll
                for (int ni = 0; ni < 4; ++ni)
                    acc[mi][ni] = __builtin_amdgcn_mfma_f32_16x16x32_f16(af[mi], bf[ni], acc[mi][ni], 0, 0, 0);
        }
        if (h == 1) __syncthreads();            // all Zt reads done before overwrite
        // epilogue -> Z1 slots (col>>3)^(row&7): h=0 -> 0..31, h=1 -> 32..63
        #pragma unroll
        for (int mi = 0; mi < 2; ++mi)
            #pragma unroll
            for (int j = 0; j < 4; ++j) {
                const int row = wm2 * 32 + mi * 16 + lgrp * 4 + j;
                #pragma unroll
                for (int ni = 0; ni < 4; ++ni) {
                    const int col = h * 256 + wn2 * 64 + ni * 16 + lrow;
                    const int slot = (col >> 3) ^ (row & 7);
                    Z1[row * 512 + (slot << 3) + (col & 7)] =
                        (_Float16)fmaxf(scl1[ni] * acc[mi][ni][j] + shf1[ni], 0.0f);
                }
            }
    }

    // ---------------- phase 2: Hout = relu(bn2(Z1 @ w2 + b2)) + Hin ----------------
    float scl2[4], shf2[4];
    #pragma unroll
    for (int ni = 0; ni < 4; ++ni) {
        const int c = wn2 * 64 + ni * 16 + lrow;
        const float s = og[c] * rsqrtf(ov[c] + BN_EPS);
        scl2[ni] = s;
        shf2[ni] = s * (b2l[c] - om[c]) + ob[c];
    }
    f32x4 acc2[2][4];
    #pragma unroll
    for (int i = 0; i < 2; ++i)
        #pragma unroll
        for (int j = 0; j < 4; ++j) acc2[i][j] = zero4;

    SLOAD_B(W2T, 0, 512);
    #pragma unroll 1
    for (int ks = 0; ks < 16; ++ks) {
        __syncthreads();                        // (a) prior Bs reads + Z1 epi writes done
        SWRITE_B();
        __syncthreads();                        // (b)
        if (ks + 1 < 16) SLOAD_B(W2T, (ks + 1) * 32, 512);
        const int k0 = ks * 32;
        f16x8 af[2], bf[4];
        #pragma unroll
        for (int mi = 0; mi < 2; ++mi) {
            const int ar = arA + mi * 16;
            const int slot = ((k0 >> 3) + lgrp) ^ (ar & 7);
            af[mi] = *(const f16x8*)&Z1[ar * 512 + (slot << 3)];
        }
        #pragma unroll
        for (int ni = 0; ni < 4; ++ni) {
            const int br = wn2 * 64 + ni * 16 + lrow;
            bf[ni] = Bs[br * 4 + (lgrp ^ ((br >> 1) & 3))];
        }
        #pragma unroll
        for (int mi = 0; mi < 2; ++mi)
            #pragma unroll
            for (int ni = 0; ni < 4; ++ni)
                acc2[mi][ni] = __builtin_amdgcn_mfma_f32_16x16x32_f16(af[mi], bf[ni], acc2[mi][ni], 0, 0, 0);
    }
    #undef SLOAD_B
    #undef SWRITE_B

    #pragma unroll
    for (int mi = 0; mi < 2; ++mi)
        #pragma unroll
        for (int j = 0; j < 4; ++j) {
            const int row = m0 + wm2 * 32 + mi * 16 + lgrp * 4 + j;
            #pragma unroll
            for (int ni = 0; ni < 4; ++ni) {
                const int col = wn2 * 64 + ni * 16 + lrow;
                float v = fmaxf(scl2[ni] * acc2[mi][ni][j] + shf2[ni], 0.0f);
                v += (float)Hin[(size_t)row * H + col];
                Hout[(size_t)row * H + col] = (_Float16)v;
            }
        }
}

// ---------------- fp16 MFMA GEMM (encoder / ebond / classifier) ----------------
// EPI 0: relu(bn(acc+bias))  EPI 2: acc+bias only
template <int KDIM, int EPI>
__global__ __launch_bounds__(256, 4) void gemm_f16(
    const _Float16* __restrict__ A,
    const _Float16* __restrict__ BT,
    int Ncols,
    const float* __restrict__ bias, const float* __restrict__ bng,
    const float* __restrict__ bnb, const float* __restrict__ bnm,
    const float* __restrict__ bnv,
    _Float16* __restrict__ C16, const _Float16* __restrict__ res)
{
    __shared__ f16x8 As[2][512];
    __shared__ f16x8 Bs[2][512];

    const int tid = threadIdx.x;
    const int nt = Ncols >> 7;
    const int nwg = gridDim.x, orig = blockIdx.x;
    const int q = nwg >> 3, r = nwg & 7;
    const int xcd = orig & 7, rk = orig >> 3;
    const int wg = (xcd < r ? xcd * (q + 1) : r * (q + 1) + (xcd - r) * q) + rk;
    const int m0 = (wg / nt) * 128;
    const int n0 = (wg % nt) * 128;

    const int wid = tid >> 6, lane = tid & 63;
    const int wm = wid >> 1, wn = wid & 1;
    const int lrow = lane & 15, lgrp = lane >> 4;
    const int r0s = tid >> 2;
    const int kq  = tid & 3;
    const int sw0 = kq ^ ((r0s >> 1) & 3);
    const int sw1 = kq ^ (((r0s + 64) >> 1) & 3);

    f32x4 acc[4][4];
    const f32x4 zero4 = {0.0f, 0.0f, 0.0f, 0.0f};
    #pragma unroll
    for (int i = 0; i < 4; ++i)
        #pragma unroll
        for (int j = 0; j < 4; ++j) acc[i][j] = zero4;

    f16x8 a0, a1, b0, b1;
    #define SLOAD(K0)                                                             \
        a0 = *(const f16x8*)(A  + (size_t)(m0 + r0s) * KDIM + (K0) + kq * 8);     \
        a1 = *(const f16x8*)(A  + (size_t)(m0 + r0s + 64) * KDIM + (K0) + kq * 8);\
        b0 = *(const f16x8*)(BT + (size_t)(n0 + r0s) * KDIM + (K0) + kq * 8);     \
        b1 = *(const f16x8*)(BT + (size_t)(n0 + r0s + 64) * KDIM + (K0) + kq * 8);
    #define SWRITE(CUR)                                                           \
        As[CUR][r0s * 4 + sw0] = a0;  As[CUR][(r0s + 64) * 4 + sw1] = a1;         \
        Bs[CUR][r0s * 4 + sw0] = b0;  Bs[CUR][(r0s + 64) * 4 + sw1] = b1;

    SLOAD(0);
    int cur = 0;
    for (int k0 = 0; k0 < KDIM; k0 += 32) {
        SWRITE(cur);
        __syncthreads();
        if (k0 + 32 < KDIM) { SLOAD(k0 + 32); }
        f16x8 af[4], bf[4];
        #pragma unroll
        for (int mi = 0; mi < 4; ++mi) {
            const int ar = wm * 64 + mi * 16 + lrow;
            af[mi] = As[cur][ar * 4 + (lgrp ^ ((ar >> 1) & 3))];
        }
        #pragma unroll
        for (int ni = 0; ni < 4; ++ni) {
            const int br = wn * 64 + ni * 16 + lrow;
            bf[ni] = Bs[cur][br * 4 + (lgrp ^ ((br >> 1) & 3))];
        }
        #pragma unroll
        for (int mi = 0; mi < 4; ++mi)
            #pragma unroll
            for (int ni = 0; ni < 4; ++ni)
                acc[mi][ni] = __builtin_amdgcn_mfma_f32_16x16x32_f16(af[mi], bf[ni], acc[mi][ni], 0, 0, 0);
        cur ^= 1;
    }
    #undef SLOAD
    #undef SWRITE

    float scl[4], shf[4];
    #pragma unroll
    for (int ni = 0; ni < 4; ++ni) {
        const int c = n0 + wn * 64 + ni * 16 + lrow;
        if (EPI == 2) {
            scl[ni] = 1.0f;
            shf[ni] = bias[c];
        } else {
            const float s = bng[c] * rsqrtf(bnv[c] + BN_EPS);
            scl[ni] = s;
            shf[ni] = s * (bias[c] - bnm[c]) + bnb[c];
        }
    }
    #pragma unroll
    for (int mi = 0; mi < 4; ++mi)
        #pragma unroll
        for (int j = 0; j < 4; ++j) {
            const int row = m0 + wm * 64 + mi * 16 + lgrp * 4 + j;
            #pragma unroll
            for (int ni = 0; ni < 4; ++ni) {
                const int col = n0 + wn * 64 + ni * 16 + lrow;
                float v = scl[ni] * acc[mi][ni][j] + shf[ni];
                if (EPI != 2) v = fmaxf(v, 0.0f);
                C16[(size_t)row * Ncols + col] = (_Float16)v;
            }
        }
}

// ---------------- pooling: mean + max per graph, fp16 out ----------------
__global__ __launch_bounds__(H) void pool_kernel(const _Float16* __restrict__ h16,
                                                 const int* __restrict__ batch,
                                                 _Float16* __restrict__ p16) {
    const int g = blockIdx.x;
    const int c = threadIdx.x;
    int lo, hi;
    {
        int a = 0, b = NA;
        while (a < b) { int mid = (a + b) >> 1; if (batch[mid] < g) a = mid + 1; else b = mid; }
        lo = a;
        b = NA;
        while (a < b) { int mid = (a + b) >> 1; if (batch[mid] < g + 1) a = mid + 1; else b = mid; }
        hi = a;
    }
    float sum = 0.0f, mx = -INFINITY;
    for (int n = lo; n < hi; ++n) {
        const float v = (float)h16[(size_t)n * H + c];
        sum += v;
        mx = fmaxf(mx, v);
    }
    const int cnt = hi - lo;
    const float mean = (cnt > 0) ? sum / (float)cnt : 0.0f;
    if (cnt == 0) mx = 0.0f;
    p16[(size_t)g * H2 + c] = (_Float16)mean;
    p16[(size_t)g * H2 + H + c] = (_Float16)mx;
}

// ---------------- final linear ----------------
__global__ __launch_bounds__(64) void final_out(const _Float16* __restrict__ q2,
                                                const float* __restrict__ w,
                                                const float* __restrict__ b,
                                                float* __restrict__ out) {
    const int g = blockIdx.x;
    const int lane = threadIdx.x;
    float acc = (float)q2[(size_t)g * 128 + lane] * w[lane]
              + (float)q2[(size_t)g * 128 + 64 + lane] * w[64 + lane];
    #pragma unroll
    for (int off = 32; off > 0; off >>= 1) acc += __shfl_down(acc, off);
    if (lane == 0) out[g] = acc + b[0];
}

// ---------------- launch ----------------
extern "C" void kernel_launch(void* const* d_in, const int* in_sizes, int n_in,
                              void* d_out, int out_size, void* d_ws, size_t ws_size,
                              hipStream_t stream) {
    const float* x      = (const float*)d_in[0];
    const int*   ei     = (const int*)d_in[1];
    const int*   batch  = (const int*)d_in[2];
    const float* eattr  = (const float*)d_in[3];
    const float* enc_w  = (const float*)d_in[4];
    const float* enc_b  = (const float*)d_in[5];
    const float* bond_w = (const float*)d_in[6];
    const float* bond_b = (const float*)d_in[7];
    const float* eps    = (const float*)d_in[8];
    const float* w1     = (const float*)d_in[9];
    const float* b1     = (const float*)d_in[10];
    const float* ibn_g  = (const float*)d_in[11];
    const float* ibn_b  = (const float*)d_in[12];
    const float* ibn_m  = (const float*)d_in[13];
    const float* ibn_v  = (const float*)d_in[14];
    const float* w2     = (const float*)d_in[15];
    const float* b2     = (const float*)d_in[16];
    const float* obn_g  = (const float*)d_in[17];
    const float* obn_b  = (const float*)d_in[18];
    const float* obn_m  = (const float*)d_in[19];
    const float* obn_v  = (const float*)d_in[20];
    const float* cw1    = (const float*)d_in[21];
    const float* cb1    = (const float*)d_in[22];
    const float* c1g    = (const float*)d_in[23];
    const float* c1b    = (const float*)d_in[24];
    const float* c1m    = (const float*)d_in[25];
    const float* c1v    = (const float*)d_in[26];
    const float* cw2    = (const float*)d_in[27];
    const float* cb2    = (const float*)d_in[28];
    const float* c2g    = (const float*)d_in[29];
    const float* c2b    = (const float*)d_in[30];
    const float* c2m    = (const float*)d_in[31];
    const float* c2v    = (const float*)d_in[32];
    const float* cw3    = (const float*)d_in[33];
    const float* cb3    = (const float*)d_in[34];
    float* out = (float*)d_out;

    // ---- workspace layout (fp16 datapath; h ping-pong hA/hB; no z) ----
    const size_t WTE       = (size_t)NL * H * H2;
    const size_t CW1E      = (size_t)H2 * H;
    const size_t CW2E      = (size_t)H * (H / 2);
    const size_t EWE       = (size_t)H * KP;
    const size_t BWE       = (size_t)H * KP;
    const size_t wt_bytes  = (2 * WTE + CW1E + CW2E + EWE + BWE) * 2;
    const size_t csr_words = (size_t)3 * NA + 1 + 2 * (size_t)NE + 63;
    const size_t csr_bytes = csr_words * 4;
    const size_t eb_bytes  = (size_t)NE * H * 2;             // 134 MB
    const size_t hx_bytes  = (size_t)NA * H * 2;             // 67 MB each
    const size_t x16_bytes = (size_t)NA * KP * 2;            // 8.4 MB
    const size_t ea_bytes  = (size_t)NE * KP * 2;            // 16.8 MB
    const size_t need_full = wt_bytes + csr_bytes + eb_bytes + 2 * hx_bytes
                           + x16_bytes + ea_bytes;

    char* buf;
    if (ws_size >= need_full) { buf = (char*)d_ws; }
    else if (g_buf)           { buf = g_buf; }
    else                      { buf = (char*)d_ws; }

    _Float16* w1T  = (_Float16*)buf;
    _Float16* w2T  = w1T + WTE;
    _Float16* cw1T = w2T + WTE;
    _Float16* cw2T = cw1T + CW1E;
    _Float16* encT = cw2T + CW2E;
    _Float16* bndT = encT + EWE;
    int*  deg    = (int*)(buf + wt_bytes);
    int*  rowptr = deg + NA;
    int*  cursor = rowptr + NA + 1;
    int2* se     = (int2*)(cursor + NA);
    _Float16* eb  = (_Float16*)(buf + wt_bytes + csr_bytes);
    _Float16* hA  = (_Float16*)((char*)eb + eb_bytes);
    _Float16* hB  = (_Float16*)((char*)hA + hx_bytes);
    _Float16* x16  = (_Float16*)((char*)hB + hx_bytes);
    _Float16* ea16 = (_Float16*)((char*)x16 + x16_bytes);

    // after 5 layers (A->B->A->B->A->B) final state is in hB; classifier aliases hA
    _Float16* p16 = hA;                       // NG*H2  (hA dead after layer 4)
    _Float16* q1  = p16 + (size_t)NG * H2;    // NG*H
    _Float16* q2  = q1 + (size_t)NG * H;      // NG*(H/2)

    // ---- weight prep (transpose to fp16), once per call ----
    prep_w_all<<<dim3(H / 32, H2 / 32, NL), 256, 0, stream>>>(w1, H, H2, w1T);
    prep_w_all<<<dim3(H2 / 32, H / 32, NL), 256, 0, stream>>>(w2, H2, H, w2T);
    prep_w_all<<<dim3(H2 / 32, H / 32, 1), 256, 0, stream>>>(cw1, H2, H, cw1T);
    prep_w_all<<<dim3(H / 32, H / 64, 1), 256, 0, stream>>>(cw2, H, H / 2, cw2T);
    prep_wpad<<<1, 256, 0, stream>>>(enc_w, FN, encT);
    prep_wpad<<<1, 256, 0, stream>>>(bond_w, FE, bndT);

    // ---- CSR build ----
    hipMemsetAsync(deg, 0, (size_t)NA * 4, stream);
    count_deg<<<NE / 256, 256, 0, stream>>>(ei, deg);
    scan_deg<<<1, 1024, 0, stream>>>(deg, rowptr, cursor);
    fill_elist<<<NE / 256, 256, 0, stream>>>(ei, cursor, se);

    // ---- inputs to fp16 (padded K=32) ----
    prep_x16<<<NA / 64, 256, 0, stream>>>(x, x16);
    prep_ea16<<<NE / 64, 256, 0, stream>>>(eattr, se, ea16);

    // ---- encoder + bond encoding as MFMA GEMMs ----
    gemm_f16<KP, 2><<<(NA / 128) * (H / 128), 256, 0, stream>>>(
        x16, encT, H, enc_b, nullptr, nullptr, nullptr, nullptr, hA, nullptr);
    gemm_f16<KP, 2><<<(NE / 128) * (H / 128), 256, 0, stream>>>(
        ea16, bndT, H, bond_b, nullptr, nullptr, nullptr, nullptr, eb, nullptr);

    for (int l = 0; l < NL; ++l) {
        _Float16* hin  = (l & 1) ? hB : hA;
        _Float16* hout = (l & 1) ? hA : hB;
        fused_gine_mlp<<<NA / 64, 512, 0, stream>>>(
            hin, hout, eb, se, rowptr, eps, l,
            w1T + (size_t)l * H * H2, w2T + (size_t)l * H2 * H,
            b1 + (size_t)l * H2, ibn_g + (size_t)l * H2, ibn_b + (size_t)l * H2,
            ibn_m + (size_t)l * H2, ibn_v + (size_t)l * H2,
            b2 + (size_t)l * H, obn_g + (size_t)l * H, obn_b + (size_t)l * H,
            obn_m + (size_t)l * H, obn_v + (size_t)l * H);
    }

    pool_kernel<<<NG, H, 0, stream>>>(hB, batch, p16);
    gemm_f16<H2, 0><<<(NG / 128) * (H / 128), 256, 0, stream>>>(
        p16, cw1T, H, cb1, c1g, c1b, c1m, c1v, q1, nullptr);
    gemm_f16<H, 0><<<(NG / 128) * ((H / 2) / 128), 256, 0, stream>>>(
        q1, cw2T, H / 2, cb2, c2g, c2b, c2m, c2v, q2, nullptr);
    final_out<<<NG, 64, 0, stream>>>(q2, cw3, cb3, out);
}